// Round 5
// baseline (146.912 us; speedup 1.0000x reference)
//
#include <hip/hip_runtime.h>
#include <math.h>

#define NN 50000
#define NE 800000
#define NH 4
#define HD 32
#define FD 128      // NH*HD == IN_DIM
#define NTILE 3125  // 50000 / 16 exactly
#define GEMM_BLOCKS 512                 // grid-stride, 8 waves/block, 2 blocks/CU
#define ROWS_BLOCKS ((NE + 511) / 512)  // 1563
#define NG 12500    // aggregate node-groups (4 nodes each)
#define AGG_BLOCKS 2048                 // persistent grid-stride blocks (8/CU)
#define GCAP 256    // edges per group buffer (1 edge/thread fast path)

typedef __attribute__((ext_vector_type(8))) short short8;
typedef __attribute__((ext_vector_type(4))) float floatx4;

__device__ __forceinline__ unsigned short f2bf(float f) {
    union { float f; unsigned u; } v; v.f = f;
    unsigned u = v.u;
    return (unsigned short)((u + 0x7FFFu + ((u >> 16) & 1u)) >> 16);
}
__device__ __forceinline__ float bfu(unsigned short u) {
    union { unsigned u; float f; } v; v.u = (unsigned)u << 16; return v.f;
}
__device__ __forceinline__ float bf_lo(unsigned u) {
    union { unsigned u; float f; } v; v.u = u << 16; return v.f;
}
__device__ __forceinline__ float bf_hi(unsigned u) {
    union { unsigned u; float f; } v; v.u = u & 0xFFFF0000u; return v.f;
}

// ---------------------------------------------------------------------------
// Kernel 1: projection via bf16 MFMA. el/er computed by 4 EXTRA MFMAs against
// a per-block precomputed Wa = W^T [a_l | a_r] tile (el = x.(W^T a_l)) — no
// cross-lane shuffle reduce. CSR row-offset builder fused as trailing blocks.
// (identical to the round-3 130.8 µs build)
// ---------------------------------------------------------------------------
__global__ __launch_bounds__(512) void k_gemm_rows(const float* __restrict__ x,
                                                   const float* __restrict__ W,
                                                   const float* __restrict__ al,
                                                   const float* __restrict__ ar,
                                                   const int* __restrict__ dst,
                                                   unsigned short* __restrict__ feat_bf,
                                                   float* __restrict__ el,
                                                   float* __restrict__ er,
                                                   int* __restrict__ rows) {
    const int tid = threadIdx.x;

    if (blockIdx.x >= GEMM_BLOCKS) {
        // ---- CSR row offsets from sorted dst ----
        int e = (blockIdx.x - GEMM_BLOCKS) * 512 + tid;
        if (e < NE) {
            int dj = dst[e];
            if (e == 0) {
                for (int n = 0; n <= dj; ++n) rows[n] = 0;
            } else {
                int prev = dst[e - 1];
                for (int n = prev + 1; n <= dj; ++n) rows[n] = e;
            }
            if (e == NE - 1) {
                for (int n = dj + 1; n <= NN; ++n) rows[n] = NE;
            }
        }
        return;
    }

    __shared__ unsigned short Wl[FD * 136];    // Wl[c][k], row stride 136 bf16
    __shared__ unsigned short WaL[16 * 136];   // Wa[c][k]: c<8 = W^T[a_l|a_r], c>=8 zero
    __shared__ float aS[2 * FD];               // al | ar

    for (int p = tid; p < FD * 64; p += 512) {
        int c = p >> 6, k2 = (p & 63) * 2;
        float2 wv = *(const float2*)&W[c * FD + k2];
        *(unsigned*)&Wl[c * 136 + k2] =
            (unsigned)f2bf(wv.x) | ((unsigned)f2bf(wv.y) << 16);
    }
    if (tid < FD) aS[tid] = al[tid];
    else if (tid < 2 * FD) aS[tid] = ar[tid - FD];
    __syncthreads();

    // Wa[c][k] = sum_d a[c][d] * W[32h+d][k], h = c&3; one-time per block.
    for (int p = tid; p < 16 * FD; p += 512) {
        int c = p >> 7, k = p & 127;
        float v = 0.f;
        if (c < 8) {
            int h = c & 3;
            const float* av = &aS[(c >> 2) * FD + h * HD];
            const unsigned short* wl = &Wl[h * HD * 136 + k];
            #pragma unroll 8
            for (int d = 0; d < HD; ++d) v += bfu(wl[d * 136]) * av[d];
        }
        WaL[c * 136 + k] = f2bf(v);
    }
    __syncthreads();

    const int wv_id = tid >> 6, lane = tid & 63;
    const int col = lane & 15, quad = lane >> 4;

    for (int tile = blockIdx.x * 8 + wv_id; tile < NTILE; tile += GEMM_BLOCKS * 8) {
        const int n0 = tile * 16;

        short8 afrag[4];
        const float* xrow = x + (size_t)(n0 + col) * FD;
        #pragma unroll
        for (int s = 0; s < 4; ++s) {
            float4 u0 = *(const float4*)&xrow[s * 32 + quad * 8];
            float4 u1 = *(const float4*)&xrow[s * 32 + quad * 8 + 4];
            short8 a;
            a[0] = (short)f2bf(u0.x); a[1] = (short)f2bf(u0.y);
            a[2] = (short)f2bf(u0.z); a[3] = (short)f2bf(u0.w);
            a[4] = (short)f2bf(u1.x); a[5] = (short)f2bf(u1.y);
            a[6] = (short)f2bf(u1.z); a[7] = (short)f2bf(u1.w);
            afrag[s] = a;
        }

        floatx4 acc[8], acce;
        #pragma unroll
        for (int ct = 0; ct < 8; ++ct) acc[ct] = (floatx4){0.f, 0.f, 0.f, 0.f};
        acce = (floatx4){0.f, 0.f, 0.f, 0.f};

        #pragma unroll
        for (int ct = 0; ct < 8; ++ct) {
            #pragma unroll
            for (int s = 0; s < 4; ++s) {
                short8 b = *(const short8*)&Wl[(ct * 16 + col) * 136 + s * 32 + quad * 8];
                acc[ct] = __builtin_amdgcn_mfma_f32_16x16x32_bf16(afrag[s], b, acc[ct], 0, 0, 0);
            }
        }
        #pragma unroll
        for (int s = 0; s < 4; ++s) {
            short8 b = *(const short8*)&WaL[col * 136 + s * 32 + quad * 8];
            acce = __builtin_amdgcn_mfma_f32_16x16x32_bf16(afrag[s], b, acce, 0, 0, 0);
        }

        // feat store (C/D: col = lane&15, row = quad*4 + reg)
        #pragma unroll
        for (int ct = 0; ct < 8; ++ct) {
            #pragma unroll
            for (int r = 0; r < 4; ++r) {
                feat_bf[(size_t)(n0 + quad * 4 + r) * FD + ct * 16 + col] = f2bf(acc[ct][r]);
            }
        }
        // el/er store: acce col 0..3 = el heads, col 4..7 = er heads
        #pragma unroll
        for (int r = 0; r < 4; ++r) {
            int n = n0 + quad * 4 + r;
            if (col < 4)      el[n * NH + col]     = acce[r];
            else if (col < 8) er[n * NH + col - 4] = acce[r];
        }
    }
}

// ---------------------------------------------------------------------------
// Kernel 2: aggregation — PERSISTENT grid-stride blocks, double-buffered
// group pipeline. Group = 4 consecutive nodes (1 per wave). Per iteration:
//   (1) ISSUE next group's src/dst/el/er loads into registers (1 edge/thread,
//       fast path for groups <= GCAP edges) — loads fly during phase 2;
//   (2) phase 2 on current group from LDS buffer `buf` (round-3 inner loop);
//   (3) COMMIT next group's w=exp(leaky(el+er)) + src into buf^1;
//   (4) one barrier, swap buffers.
// Removes block-dispatch churn (2048 long-lived blocks vs 12500 one-shot) and
// hides the src->el->exp dependent chain under the previous group's gathers.
// Groups with >GCAP edges (prob ~1e-12 at mean 64) take a direct-global
// fallback with inline w — correct, just slower.
// ---------------------------------------------------------------------------
__global__ __launch_bounds__(256) void k_aggregate(const unsigned short* __restrict__ feat_bf,
                                                   const float* __restrict__ el,
                                                   const float* __restrict__ er,
                                                   const int* __restrict__ src,
                                                   const int* __restrict__ dst,
                                                   const int* __restrict__ rows,
                                                   float* __restrict__ out) {
    __shared__ float wS[2][GCAP * NH];   // 2 x 4 KB
    __shared__ int   sS[2][GCAP];        // 2 x 1 KB
    const int tid = threadIdx.x;
    const int wave = tid >> 6, lane = tid & 63;
    const int q = lane >> 4, lp = lane & 15, h = lp >> 2;
    const int dimoff = 8 * lp;

    int g = blockIdx.x;                  // AGG_BLOCKS <= NG always

    // ---- prologue: synchronously stage group g into buffer 0 ----
    int s0  = __builtin_amdgcn_readfirstlane(rows[g * 4]);
    int t3  = __builtin_amdgcn_readfirstlane(rows[g * 4 + 4]);
    int cnt = t3 - s0;
    if (cnt <= GCAP && s0 + tid < t3) {
        int sj = src[s0 + tid], dj = dst[s0 + tid];
        sS[0][tid] = sj;
        float4 l4 = *(const float4*)&el[sj * NH];
        float4 r4 = *(const float4*)&er[dj * NH];
        float4 w; float lg;
        lg = l4.x + r4.x; w.x = __expf(fmaxf(lg, 0.2f * lg));
        lg = l4.y + r4.y; w.y = __expf(fmaxf(lg, 0.2f * lg));
        lg = l4.z + r4.z; w.z = __expf(fmaxf(lg, 0.2f * lg));
        lg = l4.w + r4.w; w.w = __expf(fmaxf(lg, 0.2f * lg));
        *(float4*)&wS[0][tid * NH] = w;
    }
    __syncthreads();

    int buf = 0;
    for (; g < NG; g += AGG_BLOCKS) {
        const int nxt = g + AGG_BLOCKS;

        // ---- (1) issue next group's loads (no use until commit) ----
        int ns0 = 0, nt3 = 0, ncnt = 0, nsj = 0;
        float4 nl4 = make_float4(0.f, 0.f, 0.f, 0.f);
        float4 nr4 = make_float4(0.f, 0.f, 0.f, 0.f);
        bool mv = false;
        if (nxt < NG) {
            ns0  = __builtin_amdgcn_readfirstlane(rows[nxt * 4]);
            nt3  = __builtin_amdgcn_readfirstlane(rows[nxt * 4 + 4]);
            ncnt = nt3 - ns0;
            if (ncnt <= GCAP && ns0 + tid < nt3) {
                mv = true;
                int dj = dst[ns0 + tid];
                nsj = src[ns0 + tid];
                nl4 = *(const float4*)&el[nsj * NH];
                nr4 = *(const float4*)&er[dj * NH];
            }
        }

        // ---- (2) phase 2 on current group from buffer `buf` ----
        const int n = g * 4 + wave;
        const int s = __builtin_amdgcn_readfirstlane(rows[n]);
        const int t = __builtin_amdgcn_readfirstlane(rows[n + 1]);
        float acc[8] = {0.f, 0.f, 0.f, 0.f, 0.f, 0.f, 0.f, 0.f};
        float den = 0.f;

        if (cnt <= GCAP) {
            for (int e = s; e < t; e += 16) {
                const int base = e + 4 * q;
                float wv4[4];
                int   sj4[4];
                uint4 uvv[4];
                #pragma unroll
                for (int u = 0; u < 4; ++u) {
                    int ei = base + u;
                    bool v = ei < t;                   // ei >= s guaranteed
                    int ii = v ? (ei - s0) : 0;        // clamped: LDS-safe
                    sj4[u] = sS[buf][ii];
                    wv4[u] = v ? wS[buf][ii * NH + h] : 0.f;
                    if (v) uvv[u] = *(const uint4*)&feat_bf[(size_t)sj4[u] * FD + dimoff];
                }
                #pragma unroll
                for (int u = 0; u < 4; ++u) {
                    if (base + u < t) {
                        float w = wv4[u];
                        uint4 uv = uvv[u];
                        acc[0] += w * bf_lo(uv.x); acc[1] += w * bf_hi(uv.x);
                        acc[2] += w * bf_lo(uv.y); acc[3] += w * bf_hi(uv.y);
                        acc[4] += w * bf_lo(uv.z); acc[5] += w * bf_hi(uv.z);
                        acc[6] += w * bf_lo(uv.w); acc[7] += w * bf_hi(uv.w);
                        den += w;
                    }
                }
            }
        } else {
            // rare fallback: direct global, inline w
            for (int e = s; e < t; e += 16) {
                const int base = e + 4 * q;
                #pragma unroll
                for (int u = 0; u < 4; ++u) {
                    int ei = base + u;
                    if (ei < t) {
                        int sj = src[ei];
                        float lg = el[sj * NH + h] + er[n * NH + h];
                        float w = __expf(fmaxf(lg, 0.2f * lg));
                        uint4 uv = *(const uint4*)&feat_bf[(size_t)sj * FD + dimoff];
                        acc[0] += w * bf_lo(uv.x); acc[1] += w * bf_hi(uv.x);
                        acc[2] += w * bf_lo(uv.y); acc[3] += w * bf_hi(uv.y);
                        acc[4] += w * bf_lo(uv.z); acc[5] += w * bf_hi(uv.z);
                        acc[6] += w * bf_lo(uv.w); acc[7] += w * bf_hi(uv.w);
                        den += w;
                    }
                }
            }
        }

        // combine the 4 edge-groups (lane bits 4,5) and write
        #pragma unroll
        for (int m = 16; m < 64; m <<= 1) {
            #pragma unroll
            for (int j = 0; j < 8; ++j) acc[j] += __shfl_xor(acc[j], m);
            den += __shfl_xor(den, m);
        }
        if (q == 0) {
            const float rden = (den > 0.f) ? 1.f / den : 0.f;
            float* op = out + (size_t)n * FD + dimoff;
            *(float4*)op       = make_float4(acc[0] * rden, acc[1] * rden, acc[2] * rden, acc[3] * rden);
            *(float4*)(op + 4) = make_float4(acc[4] * rden, acc[5] * rden, acc[6] * rden, acc[7] * rden);
        }

        // ---- (3) commit next group's weights into buf^1 ----
        if (mv) {
            sS[buf ^ 1][tid] = nsj;
            float4 w; float lg;
            lg = nl4.x + nr4.x; w.x = __expf(fmaxf(lg, 0.2f * lg));
            lg = nl4.y + nr4.y; w.y = __expf(fmaxf(lg, 0.2f * lg));
            lg = nl4.z + nr4.z; w.z = __expf(fmaxf(lg, 0.2f * lg));
            lg = nl4.w + nr4.w; w.w = __expf(fmaxf(lg, 0.2f * lg));
            *(float4*)&wS[buf ^ 1][tid * NH] = w;
        }

        // ---- (4) barrier + swap ----
        __syncthreads();
        buf ^= 1;
        s0 = ns0; t3 = nt3; cnt = ncnt;
    }
}

// ---------------------------------------------------------------------------
extern "C" void kernel_launch(void* const* d_in, const int* in_sizes, int n_in,
                              void* d_out, int out_size, void* d_ws, size_t ws_size,
                              hipStream_t stream) {
    const float* x  = (const float*)d_in[0];
    const float* W  = (const float*)d_in[1];
    const float* al = (const float*)d_in[2];
    const float* ar = (const float*)d_in[3];
    const int* src  = (const int*)d_in[4];
    const int* dst  = (const int*)d_in[5];
    float* out = (float*)d_out;

    // ws: feat_bf[NN*FD] ushort | el[NN*NH] f32 | er[NN*NH] f32 | rows[NN+1]
    unsigned short* feat_bf = (unsigned short*)d_ws;
    float* el = (float*)(feat_bf + (size_t)NN * FD);
    float* er = el + (size_t)NN * NH;
    int*   rows = (int*)(er + (size_t)NN * NH);

    k_gemm_rows<<<GEMM_BLOCKS + ROWS_BLOCKS, 512, 0, stream>>>(x, W, al, ar, dst,
                                                               feat_bf, el, er, rows);
    k_aggregate<<<AGG_BLOCKS, 256, 0, stream>>>(feat_bf, el, er, src, dst, rows, out);
}

// Round 6
// 138.158 us; speedup vs baseline: 1.0634x; 1.0634x over previous
//
#include <hip/hip_runtime.h>
#include <math.h>

#define NN 50000
#define NE 800000
#define NH 4
#define HD 32
#define FD 128      // NH*HD == IN_DIM
#define NTILE 3125  // 50000 / 16 exactly
#define GEMM_BLOCKS 512                 // grid-stride, 8 waves/block, 2 blocks/CU
#define ROWS_BLOCKS ((NE + 511) / 512)  // 1563
#define CAP 1024    // edges per LDS chunk; wS+sS = 20 KB -> exactly 8 blocks/CU

typedef __attribute__((ext_vector_type(8))) short short8;
typedef __attribute__((ext_vector_type(4))) float floatx4;

__device__ __forceinline__ unsigned short f2bf(float f) {
    union { float f; unsigned u; } v; v.f = f;
    unsigned u = v.u;
    return (unsigned short)((u + 0x7FFFu + ((u >> 16) & 1u)) >> 16);
}
__device__ __forceinline__ float bfu(unsigned short u) {
    union { unsigned u; float f; } v; v.u = (unsigned)u << 16; return v.f;
}
__device__ __forceinline__ float bf_lo(unsigned u) {
    union { unsigned u; float f; } v; v.u = u << 16; return v.f;
}
__device__ __forceinline__ float bf_hi(unsigned u) {
    union { unsigned u; float f; } v; v.u = u & 0xFFFF0000u; return v.f;
}

// ---------------------------------------------------------------------------
// Kernel 1: projection via bf16 MFMA. el/er computed by 4 EXTRA MFMAs against
// a per-block precomputed Wa = W^T [a_l | a_r] tile (el = x.(W^T a_l)) — no
// cross-lane shuffle reduce. CSR row-offset builder fused as trailing blocks.
// (identical to the round-3 130.8 µs build)
// ---------------------------------------------------------------------------
__global__ __launch_bounds__(512) void k_gemm_rows(const float* __restrict__ x,
                                                   const float* __restrict__ W,
                                                   const float* __restrict__ al,
                                                   const float* __restrict__ ar,
                                                   const int* __restrict__ dst,
                                                   unsigned short* __restrict__ feat_bf,
                                                   float* __restrict__ el,
                                                   float* __restrict__ er,
                                                   int* __restrict__ rows) {
    const int tid = threadIdx.x;

    if (blockIdx.x >= GEMM_BLOCKS) {
        // ---- CSR row offsets from sorted dst ----
        int e = (blockIdx.x - GEMM_BLOCKS) * 512 + tid;
        if (e < NE) {
            int dj = dst[e];
            if (e == 0) {
                for (int n = 0; n <= dj; ++n) rows[n] = 0;
            } else {
                int prev = dst[e - 1];
                for (int n = prev + 1; n <= dj; ++n) rows[n] = e;
            }
            if (e == NE - 1) {
                for (int n = dj + 1; n <= NN; ++n) rows[n] = NE;
            }
        }
        return;
    }

    __shared__ unsigned short Wl[FD * 136];    // Wl[c][k], row stride 136 bf16
    __shared__ unsigned short WaL[16 * 136];   // Wa[c][k]: c<8 = W^T[a_l|a_r], c>=8 zero
    __shared__ float aS[2 * FD];               // al | ar

    for (int p = tid; p < FD * 64; p += 512) {
        int c = p >> 6, k2 = (p & 63) * 2;
        float2 wv = *(const float2*)&W[c * FD + k2];
        *(unsigned*)&Wl[c * 136 + k2] =
            (unsigned)f2bf(wv.x) | ((unsigned)f2bf(wv.y) << 16);
    }
    if (tid < FD) aS[tid] = al[tid];
    else if (tid < 2 * FD) aS[tid] = ar[tid - FD];
    __syncthreads();

    // Wa[c][k] = sum_d a[c][d] * W[32h+d][k], h = c&3; one-time per block.
    for (int p = tid; p < 16 * FD; p += 512) {
        int c = p >> 7, k = p & 127;
        float v = 0.f;
        if (c < 8) {
            int h = c & 3;
            const float* av = &aS[(c >> 2) * FD + h * HD];
            const unsigned short* wl = &Wl[h * HD * 136 + k];
            #pragma unroll 8
            for (int d = 0; d < HD; ++d) v += bfu(wl[d * 136]) * av[d];
        }
        WaL[c * 136 + k] = f2bf(v);
    }
    __syncthreads();

    const int wv_id = tid >> 6, lane = tid & 63;
    const int col = lane & 15, quad = lane >> 4;

    for (int tile = blockIdx.x * 8 + wv_id; tile < NTILE; tile += GEMM_BLOCKS * 8) {
        const int n0 = tile * 16;

        short8 afrag[4];
        const float* xrow = x + (size_t)(n0 + col) * FD;
        #pragma unroll
        for (int s = 0; s < 4; ++s) {
            float4 u0 = *(const float4*)&xrow[s * 32 + quad * 8];
            float4 u1 = *(const float4*)&xrow[s * 32 + quad * 8 + 4];
            short8 a;
            a[0] = (short)f2bf(u0.x); a[1] = (short)f2bf(u0.y);
            a[2] = (short)f2bf(u0.z); a[3] = (short)f2bf(u0.w);
            a[4] = (short)f2bf(u1.x); a[5] = (short)f2bf(u1.y);
            a[6] = (short)f2bf(u1.z); a[7] = (short)f2bf(u1.w);
            afrag[s] = a;
        }

        floatx4 acc[8], acce;
        #pragma unroll
        for (int ct = 0; ct < 8; ++ct) acc[ct] = (floatx4){0.f, 0.f, 0.f, 0.f};
        acce = (floatx4){0.f, 0.f, 0.f, 0.f};

        #pragma unroll
        for (int ct = 0; ct < 8; ++ct) {
            #pragma unroll
            for (int s = 0; s < 4; ++s) {
                short8 b = *(const short8*)&Wl[(ct * 16 + col) * 136 + s * 32 + quad * 8];
                acc[ct] = __builtin_amdgcn_mfma_f32_16x16x32_bf16(afrag[s], b, acc[ct], 0, 0, 0);
            }
        }
        #pragma unroll
        for (int s = 0; s < 4; ++s) {
            short8 b = *(const short8*)&WaL[col * 136 + s * 32 + quad * 8];
            acce = __builtin_amdgcn_mfma_f32_16x16x32_bf16(afrag[s], b, acce, 0, 0, 0);
        }

        // feat store (C/D: col = lane&15, row = quad*4 + reg)
        #pragma unroll
        for (int ct = 0; ct < 8; ++ct) {
            #pragma unroll
            for (int r = 0; r < 4; ++r) {
                feat_bf[(size_t)(n0 + quad * 4 + r) * FD + ct * 16 + col] = f2bf(acc[ct][r]);
            }
        }
        // el/er store: acce col 0..3 = el heads, col 4..7 = er heads
        #pragma unroll
        for (int r = 0; r < 4; ++r) {
            int n = n0 + quad * 4 + r;
            if (col < 4)      el[n * NH + col]     = acce[r];
            else if (col < 8) er[n * NH + col - 4] = acce[r];
        }
    }
}

// ---------------------------------------------------------------------------
// Kernel 2: aggregation (round-3 structure: 4 nodes/block, one-shot blocks,
// 2-phase LDS staging). Single change vs round 3: phase 2 issues TWO 4-gather
// batches (32 edges) back-to-back before consuming — halves the exposed
// gather latency for the ~43% of nodes with deg > 16 and doubles per-wave
// MLP. Everything else byte-identical to the 130.8 µs build.
// ---------------------------------------------------------------------------
__global__ __launch_bounds__(256) void k_aggregate(const unsigned short* __restrict__ feat_bf,
                                                   const float* __restrict__ el,
                                                   const float* __restrict__ er,
                                                   const int* __restrict__ src,
                                                   const int* __restrict__ dst,
                                                   const int* __restrict__ rows,
                                                   float* __restrict__ out) {
    __shared__ float wS[CAP * NH];   // 16 KB
    __shared__ int   sS[CAP];        // 4 KB
    const int tid = threadIdx.x;
    const int wave = tid >> 6;
    const int lane = tid & 63;
    const int n0 = blockIdx.x * 4;   // NN % 4 == 0
    const int n  = n0 + wave;

    const int s0 = __builtin_amdgcn_readfirstlane(rows[n0]);
    const int t3 = __builtin_amdgcn_readfirstlane(rows[n0 + 4]);
    const int s  = __builtin_amdgcn_readfirstlane(rows[n]);
    const int t  = __builtin_amdgcn_readfirstlane(rows[n + 1]);

    const int q  = lane >> 4;        // edge slot 0..3
    const int lp = lane & 15;        // dim slot: dims 8*lp .. 8*lp+7
    const int h  = lp >> 2;          // head of those dims
    const int dimoff = 8 * lp;

    float acc[8] = {0.f, 0.f, 0.f, 0.f, 0.f, 0.f, 0.f, 0.f};
    float den = 0.f;

    for (int c0 = s0; c0 < t3; c0 += CAP) {
        const int c1 = min(c0 + CAP, t3);

        // ---- phase 1: per-edge weights + src into LDS ----
        for (int e = c0 + tid; e < c1; e += 256) {
            int sj = src[e], dj = dst[e];
            sS[e - c0] = sj;
            float4 l4 = *(const float4*)&el[sj * NH];
            float4 r4 = *(const float4*)&er[dj * NH];
            float4 w; float lg;
            lg = l4.x + r4.x; w.x = __expf(fmaxf(lg, 0.2f * lg));
            lg = l4.y + r4.y; w.y = __expf(fmaxf(lg, 0.2f * lg));
            lg = l4.z + r4.z; w.z = __expf(fmaxf(lg, 0.2f * lg));
            lg = l4.w + r4.w; w.w = __expf(fmaxf(lg, 0.2f * lg));
            *(float4*)&wS[(e - c0) * NH] = w;
        }
        __syncthreads();

        // ---- phase 2: this wave's edges within [c0, c1), 32 per iteration ----
        const int sb = max(s, c0), tb = min(t, c1);
        for (int e = sb; e < tb; e += 32) {
            const int bA = e + 4 * q;
            const int bB = e + 16 + 4 * q;
            float wvA[4], wvB[4];
            int   sjA[4], sjB[4];
            uint4 uvA[4], uvB[4];
            // issue batch A gathers
            #pragma unroll
            for (int u = 0; u < 4; ++u) {
                int ei = bA + u;
                bool v = ei < tb;                  // ei >= sb guaranteed
                int ii = v ? (ei - c0) : 0;        // clamped: LDS-safe
                sjA[u] = sS[ii];
                wvA[u] = v ? wS[ii * NH + h] : 0.f;
                if (v) uvA[u] = *(const uint4*)&feat_bf[(size_t)sjA[u] * FD + dimoff];
            }
            // issue batch B gathers before consuming A
            #pragma unroll
            for (int u = 0; u < 4; ++u) {
                int ei = bB + u;
                bool v = ei < tb;
                int ii = v ? (ei - c0) : 0;
                sjB[u] = sS[ii];
                wvB[u] = v ? wS[ii * NH + h] : 0.f;
                if (v) uvB[u] = *(const uint4*)&feat_bf[(size_t)sjB[u] * FD + dimoff];
            }
            // consume A
            #pragma unroll
            for (int u = 0; u < 4; ++u) {
                if (bA + u < tb) {
                    float w = wvA[u];
                    uint4 uv = uvA[u];
                    acc[0] += w * bf_lo(uv.x); acc[1] += w * bf_hi(uv.x);
                    acc[2] += w * bf_lo(uv.y); acc[3] += w * bf_hi(uv.y);
                    acc[4] += w * bf_lo(uv.z); acc[5] += w * bf_hi(uv.z);
                    acc[6] += w * bf_lo(uv.w); acc[7] += w * bf_hi(uv.w);
                    den += w;
                }
            }
            // consume B
            #pragma unroll
            for (int u = 0; u < 4; ++u) {
                if (bB + u < tb) {
                    float w = wvB[u];
                    uint4 uv = uvB[u];
                    acc[0] += w * bf_lo(uv.x); acc[1] += w * bf_hi(uv.x);
                    acc[2] += w * bf_lo(uv.y); acc[3] += w * bf_hi(uv.y);
                    acc[4] += w * bf_lo(uv.z); acc[5] += w * bf_hi(uv.z);
                    acc[6] += w * bf_lo(uv.w); acc[7] += w * bf_hi(uv.w);
                    den += w;
                }
            }
        }
        __syncthreads();   // before next chunk overwrites wS/sS
    }

    // combine the 4 edge-groups (lanes differing in bits 4,5)
    #pragma unroll
    for (int m = 16; m < 64; m <<= 1) {
        #pragma unroll
        for (int j = 0; j < 8; ++j) acc[j] += __shfl_xor(acc[j], m);
        den += __shfl_xor(den, m);
    }

    if (q == 0) {
        const float rden = (den > 0.f) ? 1.f / den : 0.f;
        float* op = out + (size_t)n * FD + dimoff;
        *(float4*)op       = make_float4(acc[0] * rden, acc[1] * rden, acc[2] * rden, acc[3] * rden);
        *(float4*)(op + 4) = make_float4(acc[4] * rden, acc[5] * rden, acc[6] * rden, acc[7] * rden);
    }
}

// ---------------------------------------------------------------------------
extern "C" void kernel_launch(void* const* d_in, const int* in_sizes, int n_in,
                              void* d_out, int out_size, void* d_ws, size_t ws_size,
                              hipStream_t stream) {
    const float* x  = (const float*)d_in[0];
    const float* W  = (const float*)d_in[1];
    const float* al = (const float*)d_in[2];
    const float* ar = (const float*)d_in[3];
    const int* src  = (const int*)d_in[4];
    const int* dst  = (const int*)d_in[5];
    float* out = (float*)d_out;

    // ws: feat_bf[NN*FD] ushort | el[NN*NH] f32 | er[NN*NH] f32 | rows[NN+1]
    unsigned short* feat_bf = (unsigned short*)d_ws;
    float* el = (float*)(feat_bf + (size_t)NN * FD);
    float* er = el + (size_t)NN * NH;
    int*   rows = (int*)(er + (size_t)NN * NH);

    k_gemm_rows<<<GEMM_BLOCKS + ROWS_BLOCKS, 512, 0, stream>>>(x, W, al, ar, dst,
                                                               feat_bf, el, er, rows);
    k_aggregate<<<NN / 4, 256, 0, stream>>>(feat_bf, el, er, src, dst, rows, out);
}

// Round 8
// 130.648 us; speedup vs baseline: 1.1245x; 1.0575x over previous
//
#include <hip/hip_runtime.h>
#include <math.h>

#define NN 50000
#define NE 800000
#define NH 4
#define HD 32
#define FD 128      // NH*HD == IN_DIM
#define NTILE 3125  // 50000 / 16 exactly
#define GEMM_BLOCKS 512                 // grid-stride, 8 waves/block, 2 blocks/CU
#define ROWS_BLOCKS ((NE + 511) / 512)  // 1563
#define CAP 1024    // edges per LDS chunk; wS+sS = 20 KB -> exactly 8 blocks/CU

typedef __attribute__((ext_vector_type(8))) short short8;
typedef __attribute__((ext_vector_type(4))) float floatx4;

__device__ __forceinline__ unsigned short f2bf(float f) {
    union { float f; unsigned u; } v; v.f = f;
    unsigned u = v.u;
    return (unsigned short)((u + 0x7FFFu + ((u >> 16) & 1u)) >> 16);
}
__device__ __forceinline__ float bfu(unsigned short u) {
    union { unsigned u; float f; } v; v.u = (unsigned)u << 16; return v.f;
}
__device__ __forceinline__ float bf_lo(unsigned u) {
    union { unsigned u; float f; } v; v.u = u << 16; return v.f;
}
__device__ __forceinline__ float bf_hi(unsigned u) {
    union { unsigned u; float f; } v; v.u = u & 0xFFFF0000u; return v.f;
}

// ---------------------------------------------------------------------------
// Kernel 1: projection via bf16 MFMA. el/er computed by 4 EXTRA MFMAs against
// a per-block precomputed Wa = W^T [a_l | a_r] tile (el = x.(W^T a_l)) — no
// cross-lane shuffle reduce. CSR row-offset builder fused as trailing blocks.
// (identical to the round-3 130.8 µs build)
// ---------------------------------------------------------------------------
__global__ __launch_bounds__(512) void k_gemm_rows(const float* __restrict__ x,
                                                   const float* __restrict__ W,
                                                   const float* __restrict__ al,
                                                   const float* __restrict__ ar,
                                                   const int* __restrict__ dst,
                                                   unsigned short* __restrict__ feat_bf,
                                                   float* __restrict__ el,
                                                   float* __restrict__ er,
                                                   int* __restrict__ rows) {
    const int tid = threadIdx.x;

    if (blockIdx.x >= GEMM_BLOCKS) {
        // ---- CSR row offsets from sorted dst ----
        int e = (blockIdx.x - GEMM_BLOCKS) * 512 + tid;
        if (e < NE) {
            int dj = dst[e];
            if (e == 0) {
                for (int n = 0; n <= dj; ++n) rows[n] = 0;
            } else {
                int prev = dst[e - 1];
                for (int n = prev + 1; n <= dj; ++n) rows[n] = e;
            }
            if (e == NE - 1) {
                for (int n = dj + 1; n <= NN; ++n) rows[n] = NE;
            }
        }
        return;
    }

    __shared__ unsigned short Wl[FD * 136];    // Wl[c][k], row stride 136 bf16
    __shared__ unsigned short WaL[16 * 136];   // Wa[c][k]: c<8 = W^T[a_l|a_r], c>=8 zero
    __shared__ float aS[2 * FD];               // al | ar

    for (int p = tid; p < FD * 64; p += 512) {
        int c = p >> 6, k2 = (p & 63) * 2;
        float2 wv = *(const float2*)&W[c * FD + k2];
        *(unsigned*)&Wl[c * 136 + k2] =
            (unsigned)f2bf(wv.x) | ((unsigned)f2bf(wv.y) << 16);
    }
    if (tid < FD) aS[tid] = al[tid];
    else if (tid < 2 * FD) aS[tid] = ar[tid - FD];
    __syncthreads();

    // Wa[c][k] = sum_d a[c][d] * W[32h+d][k], h = c&3; one-time per block.
    for (int p = tid; p < 16 * FD; p += 512) {
        int c = p >> 7, k = p & 127;
        float v = 0.f;
        if (c < 8) {
            int h = c & 3;
            const float* av = &aS[(c >> 2) * FD + h * HD];
            const unsigned short* wl = &Wl[h * HD * 136 + k];
            #pragma unroll 8
            for (int d = 0; d < HD; ++d) v += bfu(wl[d * 136]) * av[d];
        }
        WaL[c * 136 + k] = f2bf(v);
    }
    __syncthreads();

    const int wv_id = tid >> 6, lane = tid & 63;
    const int col = lane & 15, quad = lane >> 4;

    for (int tile = blockIdx.x * 8 + wv_id; tile < NTILE; tile += GEMM_BLOCKS * 8) {
        const int n0 = tile * 16;

        short8 afrag[4];
        const float* xrow = x + (size_t)(n0 + col) * FD;
        #pragma unroll
        for (int s = 0; s < 4; ++s) {
            float4 u0 = *(const float4*)&xrow[s * 32 + quad * 8];
            float4 u1 = *(const float4*)&xrow[s * 32 + quad * 8 + 4];
            short8 a;
            a[0] = (short)f2bf(u0.x); a[1] = (short)f2bf(u0.y);
            a[2] = (short)f2bf(u0.z); a[3] = (short)f2bf(u0.w);
            a[4] = (short)f2bf(u1.x); a[5] = (short)f2bf(u1.y);
            a[6] = (short)f2bf(u1.z); a[7] = (short)f2bf(u1.w);
            afrag[s] = a;
        }

        floatx4 acc[8], acce;
        #pragma unroll
        for (int ct = 0; ct < 8; ++ct) acc[ct] = (floatx4){0.f, 0.f, 0.f, 0.f};
        acce = (floatx4){0.f, 0.f, 0.f, 0.f};

        #pragma unroll
        for (int ct = 0; ct < 8; ++ct) {
            #pragma unroll
            for (int s = 0; s < 4; ++s) {
                short8 b = *(const short8*)&Wl[(ct * 16 + col) * 136 + s * 32 + quad * 8];
                acc[ct] = __builtin_amdgcn_mfma_f32_16x16x32_bf16(afrag[s], b, acc[ct], 0, 0, 0);
            }
        }
        #pragma unroll
        for (int s = 0; s < 4; ++s) {
            short8 b = *(const short8*)&WaL[col * 136 + s * 32 + quad * 8];
            acce = __builtin_amdgcn_mfma_f32_16x16x32_bf16(afrag[s], b, acce, 0, 0, 0);
        }

        // feat store (C/D: col = lane&15, row = quad*4 + reg)
        #pragma unroll
        for (int ct = 0; ct < 8; ++ct) {
            #pragma unroll
            for (int r = 0; r < 4; ++r) {
                feat_bf[(size_t)(n0 + quad * 4 + r) * FD + ct * 16 + col] = f2bf(acc[ct][r]);
            }
        }
        // el/er store: acce col 0..3 = el heads, col 4..7 = er heads
        #pragma unroll
        for (int r = 0; r < 4; ++r) {
            int n = n0 + quad * 4 + r;
            if (col < 4)      el[n * NH + col]     = acce[r];
            else if (col < 8) er[n * NH + col - 4] = acce[r];
        }
    }
}

// ---------------------------------------------------------------------------
// Kernel 2: aggregation — EXACT round-3 structure (4 nodes/block, one-shot
// blocks, 2-phase LDS staging, 16-edge phase-2 batch). Two micro-edits only:
//   (a) phase 2 issues all 4 sS reads + feat gathers BEFORE the wS reads
//       (shortens ds_read -> vmem-issue critical path);
//   (b) `out` written with nontemporal stores via clang vector type
//       (write-once stream; keeps L2 capacity for the feat gather set).
// ---------------------------------------------------------------------------
__global__ __launch_bounds__(256) void k_aggregate(const unsigned short* __restrict__ feat_bf,
                                                   const float* __restrict__ el,
                                                   const float* __restrict__ er,
                                                   const int* __restrict__ src,
                                                   const int* __restrict__ dst,
                                                   const int* __restrict__ rows,
                                                   float* __restrict__ out) {
    __shared__ float wS[CAP * NH];   // 16 KB
    __shared__ int   sS[CAP];        // 4 KB
    const int tid = threadIdx.x;
    const int wave = tid >> 6;
    const int lane = tid & 63;
    const int n0 = blockIdx.x * 4;   // NN % 4 == 0
    const int n  = n0 + wave;

    const int s0 = __builtin_amdgcn_readfirstlane(rows[n0]);
    const int t3 = __builtin_amdgcn_readfirstlane(rows[n0 + 4]);
    const int s  = __builtin_amdgcn_readfirstlane(rows[n]);
    const int t  = __builtin_amdgcn_readfirstlane(rows[n + 1]);

    const int q  = lane >> 4;        // edge slot 0..3
    const int lp = lane & 15;        // dim slot: dims 8*lp .. 8*lp+7
    const int h  = lp >> 2;          // head of those dims
    const int dimoff = 8 * lp;

    float acc[8] = {0.f, 0.f, 0.f, 0.f, 0.f, 0.f, 0.f, 0.f};
    float den = 0.f;

    for (int c0 = s0; c0 < t3; c0 += CAP) {
        const int c1 = min(c0 + CAP, t3);

        // ---- phase 1: per-edge weights + src into LDS ----
        for (int e = c0 + tid; e < c1; e += 256) {
            int sj = src[e], dj = dst[e];
            sS[e - c0] = sj;
            float4 l4 = *(const float4*)&el[sj * NH];
            float4 r4 = *(const float4*)&er[dj * NH];
            float4 w; float lg;
            lg = l4.x + r4.x; w.x = __expf(fmaxf(lg, 0.2f * lg));
            lg = l4.y + r4.y; w.y = __expf(fmaxf(lg, 0.2f * lg));
            lg = l4.z + r4.z; w.z = __expf(fmaxf(lg, 0.2f * lg));
            lg = l4.w + r4.w; w.w = __expf(fmaxf(lg, 0.2f * lg));
            *(float4*)&wS[(e - c0) * NH] = w;
        }
        __syncthreads();

        // ---- phase 2: this wave's edges within [c0, c1) ----
        const int sb = max(s, c0), tb = min(t, c1);
        for (int e = sb; e < tb; e += 16) {
            const int base = e + 4 * q;
            float wv4[4];
            int   sj4[4];
            uint4 uvv[4];
            // (a) indices + gathers first: vmem issues before wS ds_reads
            #pragma unroll
            for (int u = 0; u < 4; ++u) {
                int ei = base + u;
                bool v = ei < tb;                  // ei >= sb guaranteed
                int ii = v ? (ei - c0) : 0;        // clamped: LDS-safe
                sj4[u] = sS[ii];
                if (v) uvv[u] = *(const uint4*)&feat_bf[(size_t)sj4[u] * FD + dimoff];
            }
            #pragma unroll
            for (int u = 0; u < 4; ++u) {
                int ei = base + u;
                bool v = ei < tb;
                int ii = v ? (ei - c0) : 0;
                wv4[u] = v ? wS[ii * NH + h] : 0.f;
            }
            #pragma unroll
            for (int u = 0; u < 4; ++u) {
                int ei = base + u;
                if (ei < tb) {
                    float w = wv4[u];
                    uint4 uv = uvv[u];
                    acc[0] += w * bf_lo(uv.x); acc[1] += w * bf_hi(uv.x);
                    acc[2] += w * bf_lo(uv.y); acc[3] += w * bf_hi(uv.y);
                    acc[4] += w * bf_lo(uv.z); acc[5] += w * bf_hi(uv.z);
                    acc[6] += w * bf_lo(uv.w); acc[7] += w * bf_hi(uv.w);
                    den += w;
                }
            }
        }
        __syncthreads();   // before next chunk overwrites wS/sS
    }

    // combine the 4 edge-groups (lanes differing in bits 4,5)
    #pragma unroll
    for (int m = 16; m < 64; m <<= 1) {
        #pragma unroll
        for (int j = 0; j < 8; ++j) acc[j] += __shfl_xor(acc[j], m);
        den += __shfl_xor(den, m);
    }

    if (q == 0) {
        const float rden = (den > 0.f) ? 1.f / den : 0.f;
        floatx4* op = (floatx4*)(out + (size_t)n * FD + dimoff);
        floatx4 o0 = {acc[0] * rden, acc[1] * rden, acc[2] * rden, acc[3] * rden};
        floatx4 o1 = {acc[4] * rden, acc[5] * rden, acc[6] * rden, acc[7] * rden};
        __builtin_nontemporal_store(o0, op);       // (b) write-once stream:
        __builtin_nontemporal_store(o1, op + 1);   //     don't pollute L2
    }
}

// ---------------------------------------------------------------------------
extern "C" void kernel_launch(void* const* d_in, const int* in_sizes, int n_in,
                              void* d_out, int out_size, void* d_ws, size_t ws_size,
                              hipStream_t stream) {
    const float* x  = (const float*)d_in[0];
    const float* W  = (const float*)d_in[1];
    const float* al = (const float*)d_in[2];
    const float* ar = (const float*)d_in[3];
    const int* src  = (const int*)d_in[4];
    const int* dst  = (const int*)d_in[5];
    float* out = (float*)d_out;

    // ws: feat_bf[NN*FD] ushort | el[NN*NH] f32 | er[NN*NH] f32 | rows[NN+1]
    unsigned short* feat_bf = (unsigned short*)d_ws;
    float* el = (float*)(feat_bf + (size_t)NN * FD);
    float* er = el + (size_t)NN * NH;
    int*   rows = (int*)(er + (size_t)NN * NH);

    k_gemm_rows<<<GEMM_BLOCKS + ROWS_BLOCKS, 512, 0, stream>>>(x, W, al, ar, dst,
                                                               feat_bf, el, er, rows);
    k_aggregate<<<NN / 4, 256, 0, stream>>>(feat_bf, el, er, src, dst, rows, out);
}